// Round 8
// baseline (402.243 us; speedup 1.0000x reference)
//
#include <hip/hip_runtime.h>

// QRNN fo-pool: T=65536, E=512, H=512 (kernel_size=2)
// gates[T,1536] = concat(x, shift(x)) @ W + b ; z=tanh, f,o=sigmoid
// c_t = f_t c_{t-1} + (1-f_t) z_t ; h_t = o_t c_t
// out = [hiddens (T*512) | h_last (512) | c_last (512)]  (f32)

#define T_LEN 65536
#define H3    1536
#define LC    64
#define NCHUNK 1024

typedef float f32x4 __attribute__((ext_vector_type(4)));
typedef short bf16x8 __attribute__((ext_vector_type(8)));

__device__ __forceinline__ unsigned short f2bf(float f) {
    unsigned int x = __builtin_bit_cast(unsigned int, f);
    x += 0x7fffu + ((x >> 16) & 1u);
    return (unsigned short)(x >> 16);
}
__device__ __forceinline__ float bf2f(unsigned short u) {
    return __builtin_bit_cast(float, ((unsigned int)u) << 16);
}
// fast sigmoid/tanh: v_exp_f32 (exp2) + v_rcp_f32, ~1ulp each — far below bf16 grid
__device__ __forceinline__ float fsig(float x) {
    return __builtin_amdgcn_rcpf(1.f + __builtin_amdgcn_exp2f(-1.44269504f * x));
}
__device__ __forceinline__ float ftanh(float x) {
    return 2.f * __builtin_amdgcn_rcpf(1.f + __builtin_amdgcn_exp2f(-2.88539008f * x)) - 1.f;
}

__device__ __forceinline__ void gload_lds16(const void* g, void* l) {
    __builtin_amdgcn_global_load_lds((const __attribute__((address_space(1))) void*)g,
                                     (__attribute__((address_space(3))) void*)l, 16, 0, 0);
}

#define BARX()  __builtin_amdgcn_s_barrier()
#define LGKM0() asm volatile("s_waitcnt lgkmcnt(0)" ::: "memory")
#define VM4()   asm volatile("s_waitcnt vmcnt(4)" ::: "memory")
#define VM0()   asm volatile("s_waitcnt vmcnt(0)" ::: "memory")

// ---- prep: x (f32) -> bf16 with 512-element zero prefix ------------------
__global__ void prep_x(const float* __restrict__ x, unsigned short* __restrict__ xp) {
    const long long nq = (512LL + (long long)T_LEN * 512) / 4;
    for (long long q = (long long)blockIdx.x * blockDim.x + threadIdx.x; q < nq;
         q += (long long)gridDim.x * blockDim.x) {
        ushort4 u;
        if (q < 128) {
            u.x = 0; u.y = 0; u.z = 0; u.w = 0;
        } else {
            const float4 v = *reinterpret_cast<const float4*>(x + q * 4 - 512);
            u.x = f2bf(v.x); u.y = f2bf(v.y); u.z = f2bf(v.z); u.w = f2bf(v.w);
        }
        *reinterpret_cast<ushort4*>(xp + q * 4) = u;
    }
}

// ---- prep: W [1024,1536] f32 -> Wt [1536,1024] bf16 ----------------------
__global__ void prep_w(const float* __restrict__ W, unsigned short* __restrict__ Wt) {
    const int n_el = 1024 * H3;
    for (int i = blockIdx.x * blockDim.x + threadIdx.x; i < n_el;
         i += gridDim.x * blockDim.x) {
        const int k = i / H3, n = i - k * H3;
        Wt[n * 1024 + k] = f2bf(W[i]);
    }
}

// ---- GEMM: 256x256 tile, BK=64, 8 waves (2Mx4N, 128x64 each), 8-phase ----
// LDS 128 KiB: buf b, slot s (0=A-half0,1=A-half1,2=B-half0,3=B-half1), each
// 8192 elems (128 rows x 64). Rows 128 B; 8-slot XOR swizzle slot'=slot^(row&7)
// via pre-swizzled global source (linear LDS dest) + swizzled read (rule #21).
// Per K-tile 4 phases {reads; stage 1 half; barrier; lgkm0; prio+16 MFMA; barrier}.
// Counted vmcnt(4) only at ph3/ph7 ends (tile t+1 / t+2 resident; newest 4 in flight).
__global__ __launch_bounds__(512, 1) void gemm_gates(
    const unsigned short* __restrict__ xp,
    const unsigned short* __restrict__ Wt,
    const float* __restrict__ bias,
    unsigned short* __restrict__ zfo)
{
    __shared__ unsigned short lds[2 * 4 * 8192];   // 128 KiB

    const int tid  = threadIdx.x;
    const int lane = tid & 63;
    const int wid  = tid >> 6;           // 0..7
    const int wm   = wid >> 2;           // 0..1  (M half)
    const int wn   = wid & 3;            // 0..3  (N quarter)

    // XCD-chunked swizzle (T1): 1536 blocks = 8 x 192; 6 A-panel sharers
    // land consecutively on ONE XCD; B (3 MB) L2-resident.
    const int flat = blockIdx.y * gridDim.x + blockIdx.x;   // 0..1535
    const int idx  = (flat & 7) * 192 + (flat >> 3);
    const int nb   = (idx % 6) * 256;                       // N base
    const long long t0 = (long long)(idx / 6) * 256;        // M base (time rows)

    // staging geometry: thread covers 16B at (row tid>>3, slot tid&7) of an
    // 8KB 64-row chunk; source col pre-swizzled by row&7.
    const int trow = tid >> 3;                              // 0..63
    const int scol = ((tid & 7) ^ (trow & 7)) * 8;          // elems

    auto stA = [&](int b, int h, int kb) {                  // A-half h of K-tile kb
        const int abase = (kb < 512) ? (512 + kb) : (kb - 512);
        const unsigned short* g = xp + (t0 + h * 128 + trow) * 512 + abase + scol;
        unsigned short* l = (unsigned short*)lds + b * 32768 + h * 8192 + wid * 512;
        gload_lds16(g, l);
        gload_lds16(g + 64 * 512, l + 4096);
    };
    auto stB = [&](int b, int h, int kb) {
        const unsigned short* g = Wt + (long long)(nb + h * 128 + trow) * 1024 + kb + scol;
        unsigned short* l = (unsigned short*)lds + b * 32768 + (2 + h) * 8192 + wid * 512;
        gload_lds16(g, l);
        gload_lds16(g + 64 * 1024, l + 4096);
    };

    // fragment read geometry (swizzled read matches staged involution)
    const int arow = lane & 15;
    const int q4   = lane >> 4;                             // 16B-slot quarter
    const int sA0  = ((q4)     ^ (arow & 7)) * 8;           // ks=0 col elems
    const int sA1  = ((q4 + 4) ^ (arow & 7)) * 8;           // ks=1 col elems
    const unsigned short* Ab = (const unsigned short*)lds + wm * 8192 + arow * 64;
    const unsigned short* Bb = (const unsigned short*)lds + (2 + (wn >> 1)) * 8192
                               + ((wn & 1) * 64 + arow) * 64;

    f32x4  acc[8][4] = {};
    bf16x8 a[4][2];     // m-frags (reused for m0-3 / m4-7)
    bf16x8 b[4][2];     // n-frags

    #define RD_A4(bo, mbase)                                                     \
        _Pragma("unroll")                                                        \
        for (int m = 0; m < 4; ++m) {                                            \
            a[m][0] = *(const bf16x8*)(Ab + (bo) + ((mbase) + m) * 1024 + sA0);  \
            a[m][1] = *(const bf16x8*)(Ab + (bo) + ((mbase) + m) * 1024 + sA1);  \
        }
    #define RD_B2(bo, n0)                                                        \
        _Pragma("unroll")                                                        \
        for (int n = 0; n < 2; ++n) {                                            \
            b[(n0)+n][0] = *(const bf16x8*)(Bb + (bo) + ((n0)+n) * 1024 + sA0);  \
            b[(n0)+n][1] = *(const bf16x8*)(Bb + (bo) + ((n0)+n) * 1024 + sA1);  \
        }
    #define QUAD(mh, nh)                                                         \
        __builtin_amdgcn_s_setprio(1);                                           \
        _Pragma("unroll")                                                        \
        for (int n = 0; n < 2; ++n) {                                            \
            _Pragma("unroll")                                                    \
            for (int m = 0; m < 4; ++m) {                                        \
                acc[(mh)*4+m][(nh)*2+n] = __builtin_amdgcn_mfma_f32_16x16x32_bf16( \
                    a[m][0], b[(nh)*2+n][0], acc[(mh)*4+m][(nh)*2+n], 0, 0, 0);  \
                acc[(mh)*4+m][(nh)*2+n] = __builtin_amdgcn_mfma_f32_16x16x32_bf16( \
                    a[m][1], b[(nh)*2+n][1], acc[(mh)*4+m][(nh)*2+n], 0, 0, 0);  \
            }                                                                    \
        }                                                                        \
        __builtin_amdgcn_s_setprio(0);

    // prologue: tile0 all 4 halves + tile1 {B0, A0}; wait tile0 (newest 4 fly)
    stB(0, 0, 0); stA(0, 0, 0); stA(0, 1, 0); stB(0, 1, 0);
    stB(1, 0, 64); stA(1, 0, 64);
    VM4();
    BARX();

    for (int i = 0; i < 7; ++i) {
        const int kb1 = i * 128 + 64;    // tile 2i+1 (buf1)
        const int kb2 = i * 128 + 128;   // tile 2i+2 (buf0)
        const int kb3 = i * 128 + 192;   // tile 2i+3 (buf1)
        // ---- tile 2i from buf0 ----
        { RD_A4(0, 0); RD_B2(0, 0); RD_B2(0, 2); stA(1, 1, kb1);
          BARX(); LGKM0(); QUAD(0, 0); BARX(); }                       // ph0
        { stB(1, 1, kb1);
          BARX(); LGKM0(); QUAD(0, 1); BARX(); }                       // ph1
        { RD_A4(0, 4); stB(0, 0, kb2);
          BARX(); LGKM0(); QUAD(1, 0); BARX(); }                       // ph2
        { stA(0, 0, kb2);
          BARX(); LGKM0(); QUAD(1, 1); VM4(); BARX(); }                // ph3
        // ---- tile 2i+1 from buf1 ----
        { RD_A4(32768, 0); RD_B2(32768, 0); RD_B2(32768, 2); stA(0, 1, kb2);
          BARX(); LGKM0(); QUAD(0, 0); BARX(); }                       // ph4
        { stB(0, 1, kb2);
          BARX(); LGKM0(); QUAD(0, 1); BARX(); }                       // ph5
        { RD_A4(32768, 4); stB(1, 0, kb3);
          BARX(); LGKM0(); QUAD(1, 0); BARX(); }                       // ph6
        { stA(1, 0, kb3);
          BARX(); LGKM0(); QUAD(1, 1); VM4(); BARX(); }                // ph7
    }
    // peeled i=7: tiles 14 (buf0), 15 (buf1); stage only tile15's {A1,B1}
    { RD_A4(0, 0); RD_B2(0, 0); RD_B2(0, 2); stA(1, 1, 960);
      BARX(); LGKM0(); QUAD(0, 0); BARX(); }
    { stB(1, 1, 960);
      BARX(); LGKM0(); QUAD(0, 1); BARX(); }
    { RD_A4(0, 4);
      BARX(); LGKM0(); QUAD(1, 0); BARX(); }
    { BARX(); LGKM0(); QUAD(1, 1); VM0(); BARX(); }
    { RD_A4(32768, 0); RD_B2(32768, 0); RD_B2(32768, 2);
      BARX(); LGKM0(); QUAD(0, 0); BARX(); }
    { BARX(); LGKM0(); QUAD(0, 1); BARX(); }
    { RD_A4(32768, 4);
      BARX(); LGKM0(); QUAD(1, 0); BARX(); }
    { LGKM0(); QUAD(1, 1); }

    // epilogue: bias + activation. Block spans 256 cols aligned to class
    // width 512 halves -> mixed only at granularity 256: cls uniform per block.
    const int cls = nb >> 9;             // 0=z(tanh), 1=f, 2=o (sigmoid)
    #pragma unroll
    for (int n = 0; n < 4; ++n) {
        const int col = nb + wn * 64 + n * 16 + arow;
        const float bn_ = bias[col];
        #pragma unroll
        for (int m = 0; m < 8; ++m) {
            const long long row0 = t0 + wm * 128 + m * 16 + q4 * 4;
            #pragma unroll
            for (int j = 0; j < 4; ++j) {
                float v = acc[m][n][j] + bn_;
                v = (cls == 0) ? ftanh(v) : fsig(v);
                zfo[(row0 + j) * H3 + col] = f2bf(v);
            }
        }
    }
}

// ---- scan pass 1: per-chunk local scan (c_init=0) + product of f ---------
__global__ void scan_pass1(const unsigned short* __restrict__ zfo,
                           float* __restrict__ P, float* __restrict__ L) {
    const int chunk = blockIdx.x;
    const int c4    = threadIdx.x;           // 0..127
    const unsigned short* base = zfo + (long long)chunk * LC * H3 + c4 * 4;
    float c[4] = {0.f, 0.f, 0.f, 0.f};
    float p[4] = {1.f, 1.f, 1.f, 1.f};
    for (int t = 0; t < LC; ++t) {
        const unsigned short* row = base + t * H3;
        const ushort4 uz = *reinterpret_cast<const ushort4*>(row);
        const ushort4 uf = *reinterpret_cast<const ushort4*>(row + 512);
        const float z[4] = {bf2f(uz.x), bf2f(uz.y), bf2f(uz.z), bf2f(uz.w)};
        const float f[4] = {bf2f(uf.x), bf2f(uf.y), bf2f(uf.z), bf2f(uf.w)};
        #pragma unroll
        for (int j = 0; j < 4; ++j) {
            c[j] = fmaf(f[j], c[j] - z[j], z[j]);   // f*c + (1-f)*z
            p[j] *= f[j];
        }
    }
    #pragma unroll
    for (int j = 0; j < 4; ++j) {
        P[chunk * 512 + c4 * 4 + j] = p[j];
        L[chunk * 512 + c4 * 4 + j] = c[j];
    }
}

// ---- scan pass 2: parallel affine-composition scan over chunks -----------
__global__ __launch_bounds__(1024) void scan_pass2(
    const float* __restrict__ P, const float* __restrict__ L,
    float* __restrict__ carry, float* __restrict__ out) {
    const int ch = blockIdx.x;
    const int k  = threadIdx.x;
    __shared__ float sP[1024], sL[1024];
    float p = P[k * 512 + ch];
    float l = L[k * 512 + ch];
    sP[k] = p; sL[k] = l;
    __syncthreads();
    for (int d = 1; d < 1024; d <<= 1) {
        float pp = 1.f, ll = 0.f;
        if (k >= d) { pp = sP[k - d]; ll = sL[k - d]; }
        __syncthreads();
        l = fmaf(p, ll, l);
        p = p * pp;
        sP[k] = p; sL[k] = l;
        __syncthreads();
    }
    carry[k * 512 + ch] = (k == 0) ? 0.f : sL[k - 1];
    if (k == 1023) out[(long long)T_LEN * 512 + 512 + ch] = l;   // cells[-1]
}

// ---- scan pass 3: replay with carry-in, write h = o*c (float4 stores) ----
__global__ void scan_pass3(const unsigned short* __restrict__ zfo,
                           const float* __restrict__ carry,
                           float* __restrict__ out) {
    const int chunk = blockIdx.x;
    const int c4    = threadIdx.x;           // 0..127
    const unsigned short* base = zfo + (long long)chunk * LC * H3 + c4 * 4;
    float c[4], h[4] = {0.f, 0.f, 0.f, 0.f};
    #pragma unroll
    for (int j = 0; j < 4; ++j) c[j] = carry[chunk * 512 + c4 * 4 + j];
    float4* outp = reinterpret_cast<float4*>(out + (long long)chunk * LC * 512) + c4;
    for (int t = 0; t < LC; ++t) {
        const unsigned short* row = base + t * H3;
        const ushort4 uz = *reinterpret_cast<const ushort4*>(row);
        const ushort4 uf = *reinterpret_cast<const ushort4*>(row + 512);
        const ushort4 uo = *reinterpret_cast<const ushort4*>(row + 1024);
        const float z[4] = {bf2f(uz.x), bf2f(uz.y), bf2f(uz.z), bf2f(uz.w)};
        const float f[4] = {bf2f(uf.x), bf2f(uf.y), bf2f(uf.z), bf2f(uf.w)};
        const float o[4] = {bf2f(uo.x), bf2f(uo.y), bf2f(uo.z), bf2f(uo.w)};
        #pragma unroll
        for (int j = 0; j < 4; ++j) {
            c[j] = fmaf(f[j], c[j] - z[j], z[j]);
            h[j] = o[j] * c[j];
        }
        float4 hv; hv.x = h[0]; hv.y = h[1]; hv.z = h[2]; hv.w = h[3];
        outp[t * 128] = hv;
    }
    if (chunk == NCHUNK - 1) {
        #pragma unroll
        for (int j = 0; j < 4; ++j)
            out[(long long)T_LEN * 512 + c4 * 4 + j] = h[j];     // hiddens[-1]
    }
}

extern "C" void kernel_launch(void* const* d_in, const int* in_sizes, int n_in,
                              void* d_out, int out_size, void* d_ws, size_t ws_size,
                              hipStream_t stream) {
    const float* x = (const float*)d_in[0];   // [65536, 512]
    const float* W = (const float*)d_in[1];   // [1024, 1536]
    const float* b = (const float*)d_in[2];   // [1536]
    float* out = (float*)d_out;

    char* ws = (char*)d_ws;
    unsigned short* xp  = (unsigned short*)(ws);                 // 67,109,888 B (+pad)
    unsigned short* Wt  = (unsigned short*)(ws + 67110912LL);    // 3,145,728 B
    unsigned short* zfo = (unsigned short*)(ws + 70256640LL);    // 201,326,592 B
    // P/L/carry reuse the xp region (dead after GEMM)
    float* P     = (float*)(ws);
    float* L     = (float*)(ws + 4194304LL);
    float* carry = (float*)(ws + 8388608LL);

    prep_x<<<4096, 256, 0, stream>>>(x, xp);
    prep_w<<<768, 256, 0, stream>>>(W, Wt);

    dim3 gg(H3 / 256, T_LEN / 256, 1);     // 6 x 256 = 1536 blocks
    gemm_gates<<<gg, 512, 0, stream>>>(xp, Wt, b, zfo);

    scan_pass1<<<NCHUNK, 128, 0, stream>>>(zfo, P, L);
    scan_pass2<<<512, 1024, 0, stream>>>(P, L, carry, out);
    scan_pass3<<<NCHUNK, 128, 0, stream>>>(zfo, carry, out);
}

// Round 9
// 377.791 us; speedup vs baseline: 1.0647x; 1.0647x over previous
//
#include <hip/hip_runtime.h>

// QRNN fo-pool: T=65536, E=512, H=512 (kernel_size=2)
// gates[T,1536] = concat(x, shift(x)) @ W + b ; z=tanh, f,o=sigmoid
// c_t = f_t c_{t-1} + (1-f_t) z_t ; h_t = o_t c_t
// out = [hiddens (T*512) | h_last (512) | c_last (512)]  (f32)

#define T_LEN 65536
#define H3    1536
#define LC    64
#define NCHUNK 1024

typedef float f32x4 __attribute__((ext_vector_type(4)));
typedef short bf16x8 __attribute__((ext_vector_type(8)));

__device__ __forceinline__ unsigned short f2bf(float f) {
    unsigned int x = __builtin_bit_cast(unsigned int, f);
    x += 0x7fffu + ((x >> 16) & 1u);
    return (unsigned short)(x >> 16);
}
__device__ __forceinline__ float bf2f(unsigned short u) {
    return __builtin_bit_cast(float, ((unsigned int)u) << 16);
}
// fast sigmoid/tanh: v_exp_f32 (exp2) + v_rcp_f32, ~1ulp each — far below bf16 grid
__device__ __forceinline__ float fsig(float x) {
    return __builtin_amdgcn_rcpf(1.f + __builtin_amdgcn_exp2f(-1.44269504f * x));
}
__device__ __forceinline__ float ftanh(float x) {
    return 2.f * __builtin_amdgcn_rcpf(1.f + __builtin_amdgcn_exp2f(-2.88539008f * x)) - 1.f;
}

__device__ __forceinline__ void gload_lds16(const void* g, void* l) {
    __builtin_amdgcn_global_load_lds((const __attribute__((address_space(1))) void*)g,
                                     (__attribute__((address_space(3))) void*)l, 16, 0, 0);
}

#define VM2()   asm volatile("s_waitcnt vmcnt(2)" ::: "memory")
#define VM0()   asm volatile("s_waitcnt vmcnt(0)" ::: "memory")
#define BARX()  __builtin_amdgcn_s_barrier()

// ---- prep: x (f32) -> bf16 with 512-element zero prefix ------------------
__global__ void prep_x(const float* __restrict__ x, unsigned short* __restrict__ xp) {
    const long long nq = (512LL + (long long)T_LEN * 512) / 4;
    for (long long q = (long long)blockIdx.x * blockDim.x + threadIdx.x; q < nq;
         q += (long long)gridDim.x * blockDim.x) {
        ushort4 u;
        if (q < 128) {
            u.x = 0; u.y = 0; u.z = 0; u.w = 0;
        } else {
            const float4 v = *reinterpret_cast<const float4*>(x + q * 4 - 512);
            u.x = f2bf(v.x); u.y = f2bf(v.y); u.z = f2bf(v.z); u.w = f2bf(v.w);
        }
        *reinterpret_cast<ushort4*>(xp + q * 4) = u;
    }
}

// ---- prep: W [1024,1536] f32 -> Wt [1536,1024] bf16 ----------------------
__global__ void prep_w(const float* __restrict__ W, unsigned short* __restrict__ Wt) {
    const int n_el = 1024 * H3;
    for (int i = blockIdx.x * blockDim.x + threadIdx.x; i < n_el;
         i += gridDim.x * blockDim.x) {
        const int k = i / H3, n = i - k * H3;
        Wt[n * 1024 + k] = f2bf(W[i]);
    }
}

// ---- GEMM: 128Mx256N tile, BK=32, 4 waves of 64x128 ----------------------
// Asymmetric-depth pipeline: A (cold HBM, ~900cy) gets 4 buffers / 3-iter
// flight; B (L2-resident Wt, ~300cy) gets 2 buffers / 1-iter flight.
// Iter t: issue B(t+1) [4 loads] THEN A(t+3) [2 loads]; compute tile t;
// gate s_waitcnt vmcnt(2) = wait B(t+1) (forces A(t+1),A(t+2), both older
// and needed by t+1/t+2 anyway) leaving A(t+3)'s 2 loads in flight; barrier.
// LDS: A[4][128*32] 32KB + B[2][256*32] 32KB = 64 KiB -> 2 blocks/CU.
// XOR swizzle 16B-slot s' = s ^ ((row>>1)&3) via pre-swizzled global source
// (linear LDS dest) + swizzled read (rule #21; 0 conflicts since R4).
__global__ __launch_bounds__(256, 2) void gemm_gates(
    const unsigned short* __restrict__ xp,
    const unsigned short* __restrict__ Wt,
    const float* __restrict__ bias,
    unsigned short* __restrict__ zfo)
{
    __shared__ unsigned short Alds[4][128 * 32];
    __shared__ unsigned short Blds[2][256 * 32];

    const int tid  = threadIdx.x;
    const int lane = tid & 63;
    const int w    = tid >> 6;           // wave 0..3
    const int wm   = w >> 1, wn = w & 1; // 2x2 wave grid, each 64M x 128N

    // XCD-chunked swizzle (T1): 3072 blocks, 384/XCD; the 6 blocks sharing
    // an A-panel land consecutively on ONE XCD; B (3 MB) L2-resident.
    const int flat = blockIdx.y * gridDim.x + blockIdx.x;   // 0..3071
    const int idx  = (flat & 7) * 384 + (flat >> 3);
    const int nb   = (idx % 6) * 256;                       // N base (0..1280)
    const long long t0 = (long long)(idx / 6) * 128;        // M base (time rows)

    // staging geometry: wave-uniform LDS dest + lane*16B; pre-swizzled source col
    const int srow_l = lane >> 2;                               // 0..15
    const int scol   = (((lane & 3) ^ ((lane >> 3) & 3)) * 8);  // swizzled col (elems)

    // per-lane global pointers, strength-reduced across K-tiles.
    // A col offset f(s) = s<16 ? 512+32*s : 32*(s-16); after staging tile s,
    // delta = +32 except after s==15: -992 (the concat wrap). B: +32 always.
    const unsigned short* gA = xp + (t0 + w * 16 + srow_l) * 512 + 512 + scol;
    const unsigned short* gB = Wt + (long long)(nb + w * 16 + srow_l) * 1024 + scol;

    auto stageA = [&](unsigned short* Al) {
        gload_lds16(gA,              Al + (w * 16) * 32);
        gload_lds16(gA + 64 * 512,   Al + (64 + w * 16) * 32);
    };
    auto stageB = [&](unsigned short* Bl) {
        gload_lds16(gB,              Bl + (w * 16) * 32);
        gload_lds16(gB + 64 * 1024,  Bl + (64 + w * 16) * 32);
        gload_lds16(gB + 128 * 1024, Bl + (128 + w * 16) * 32);
        gload_lds16(gB + 192 * 1024, Bl + (192 + w * 16) * 32);
    };

    // fragment read geometry (swizzled read matches staged involution)
    const int arow  = lane & 15;
    const int swzco = (((lane >> 4) ^ ((arow >> 1) & 3)) * 8);

    f32x4 acc[4][8] = {};

    auto compute = [&](const unsigned short* Al, const unsigned short* Bl) {
        bf16x8 af[4], bfr[8];
        #pragma unroll
        for (int m = 0; m < 4; ++m)
            af[m] = *reinterpret_cast<const bf16x8*>(Al + (wm * 64 + m * 16 + arow) * 32 + swzco);
        #pragma unroll
        for (int n = 0; n < 8; ++n)
            bfr[n] = *reinterpret_cast<const bf16x8*>(Bl + (wn * 128 + n * 16 + arow) * 32 + swzco);
        #pragma unroll
        for (int n = 0; n < 8; ++n)
            #pragma unroll
            for (int m = 0; m < 4; ++m)
                acc[m][n] = __builtin_amdgcn_mfma_f32_16x16x32_bf16(af[m], bfr[n], acc[m][n], 0, 0, 0);
    };

    // prologue: B(0), A(0), A(1), A(2); wait A(0)+B(0) (A(1),A(2) = 4 fly)
    stageB(Blds[0]); gB += 32;
    stageA(Alds[0]); gA += 32;
    stageA(Alds[1]); gA += 32;
    stageA(Alds[2]); gA += 32;
    asm volatile("s_waitcnt vmcnt(4)" ::: "memory");
    BARX();

    // main loop: t = 0..27 in groups of 4 (buffer indices compile-time:
    // base%4==0 so (base+k)&3 == k&3, (base+k)&1 == k&1)
    for (int base = 0; base < 28; base += 4) {
        #pragma unroll
        for (int k = 0; k < 4; ++k) {
            stageB(Blds[(k + 1) & 1]); gB += 32;                 // B(t+1)
            stageA(Alds[(k + 3) & 3]);                           // A(t+3)
            gA += (base + k == 12) ? -992 : 32;                  // staged s=t+3; wrap after s==15
            compute(Alds[k & 3], Blds[k & 1]);                   // tile t
            VM2();                                               // B(t+1) landed; A(t+3) flies
            BARX();
        }
    }
    // peeled t=28..31
    {   // t=28: stage B(29), A(31); compute 28 (A0,B0)
        stageB(Blds[1]); gB += 32;
        stageA(Alds[3]);
        compute(Alds[0], Blds[0]);
        VM2(); BARX();
    }
    {   // t=29: stage B(30); compute 29 (A1,B1)
        stageB(Blds[0]); gB += 32;
        compute(Alds[1], Blds[1]);
        VM0(); BARX();
    }
    {   // t=30: stage B(31); compute 30 (A2,B0)
        stageB(Blds[1]);
        compute(Alds[2], Blds[0]);
        VM0(); BARX();
    }
    compute(Alds[3], Blds[1]);   // t=31

    // epilogue: bias + activation. Block spans 256 cols, class width 512,
    // nb multiple of 256 -> single class per block: cls = nb>>9.
    const int cls = nb >> 9;             // 0=z(tanh), 1=f, 2=o (sigmoid)
    #pragma unroll
    for (int n = 0; n < 8; ++n) {
        const int col = nb + wn * 128 + n * 16 + arow;
        const float bn_ = bias[col];
        #pragma unroll
        for (int m = 0; m < 4; ++m) {
            const long long row0 = t0 + wm * 64 + m * 16 + (lane >> 4) * 4;
            #pragma unroll
            for (int j = 0; j < 4; ++j) {
                float v = acc[m][n][j] + bn_;
                v = (cls == 0) ? ftanh(v) : fsig(v);
                zfo[(row0 + j) * H3 + col] = f2bf(v);
            }
        }
    }
}

// ---- scan pass 1: per-chunk local scan (c_init=0) + product of f ---------
__global__ void scan_pass1(const unsigned short* __restrict__ zfo,
                           float* __restrict__ P, float* __restrict__ L) {
    const int chunk = blockIdx.x;
    const int c4    = threadIdx.x;           // 0..127
    const unsigned short* base = zfo + (long long)chunk * LC * H3 + c4 * 4;
    float c[4] = {0.f, 0.f, 0.f, 0.f};
    float p[4] = {1.f, 1.f, 1.f, 1.f};
    for (int t = 0; t < LC; ++t) {
        const unsigned short* row = base + t * H3;
        const ushort4 uz = *reinterpret_cast<const ushort4*>(row);
        const ushort4 uf = *reinterpret_cast<const ushort4*>(row + 512);
        const float z[4] = {bf2f(uz.x), bf2f(uz.y), bf2f(uz.z), bf2f(uz.w)};
        const float f[4] = {bf2f(uf.x), bf2f(uf.y), bf2f(uf.z), bf2f(uf.w)};
        #pragma unroll
        for (int j = 0; j < 4; ++j) {
            c[j] = fmaf(f[j], c[j] - z[j], z[j]);   // f*c + (1-f)*z
            p[j] *= f[j];
        }
    }
    #pragma unroll
    for (int j = 0; j < 4; ++j) {
        P[chunk * 512 + c4 * 4 + j] = p[j];
        L[chunk * 512 + c4 * 4 + j] = c[j];
    }
}

// ---- scan pass 2: parallel affine-composition scan over chunks -----------
__global__ __launch_bounds__(1024) void scan_pass2(
    const float* __restrict__ P, const float* __restrict__ L,
    float* __restrict__ carry, float* __restrict__ out) {
    const int ch = blockIdx.x;
    const int k  = threadIdx.x;
    __shared__ float sP[1024], sL[1024];
    float p = P[k * 512 + ch];
    float l = L[k * 512 + ch];
    sP[k] = p; sL[k] = l;
    __syncthreads();
    for (int d = 1; d < 1024; d <<= 1) {
        float pp = 1.f, ll = 0.f;
        if (k >= d) { pp = sP[k - d]; ll = sL[k - d]; }
        __syncthreads();
        l = fmaf(p, ll, l);
        p = p * pp;
        sP[k] = p; sL[k] = l;
        __syncthreads();
    }
    carry[k * 512 + ch] = (k == 0) ? 0.f : sL[k - 1];
    if (k == 1023) out[(long long)T_LEN * 512 + 512 + ch] = l;   // cells[-1]
}

// ---- scan pass 3: replay with carry-in, write h = o*c (float4 stores) ----
__global__ void scan_pass3(const unsigned short* __restrict__ zfo,
                           const float* __restrict__ carry,
                           float* __restrict__ out) {
    const int chunk = blockIdx.x;
    const int c4    = threadIdx.x;           // 0..127
    const unsigned short* base = zfo + (long long)chunk * LC * H3 + c4 * 4;
    float c[4], h[4] = {0.f, 0.f, 0.f, 0.f};
    #pragma unroll
    for (int j = 0; j < 4; ++j) c[j] = carry[chunk * 512 + c4 * 4 + j];
    float4* outp = reinterpret_cast<float4*>(out + (long long)chunk * LC * 512) + c4;
    for (int t = 0; t < LC; ++t) {
        const unsigned short* row = base + t * H3;
        const ushort4 uz = *reinterpret_cast<const ushort4*>(row);
        const ushort4 uf = *reinterpret_cast<const ushort4*>(row + 512);
        const ushort4 uo = *reinterpret_cast<const ushort4*>(row + 1024);
        const float z[4] = {bf2f(uz.x), bf2f(uz.y), bf2f(uz.z), bf2f(uz.w)};
        const float f[4] = {bf2f(uf.x), bf2f(uf.y), bf2f(uf.z), bf2f(uf.w)};
        const float o[4] = {bf2f(uo.x), bf2f(uo.y), bf2f(uo.z), bf2f(uo.w)};
        #pragma unroll
        for (int j = 0; j < 4; ++j) {
            c[j] = fmaf(f[j], c[j] - z[j], z[j]);
            h[j] = o[j] * c[j];
        }
        float4 hv; hv.x = h[0]; hv.y = h[1]; hv.z = h[2]; hv.w = h[3];
        outp[t * 128] = hv;
    }
    if (chunk == NCHUNK - 1) {
        #pragma unroll
        for (int j = 0; j < 4; ++j)
            out[(long long)T_LEN * 512 + c4 * 4 + j] = h[j];     // hiddens[-1]
    }
}

extern "C" void kernel_launch(void* const* d_in, const int* in_sizes, int n_in,
                              void* d_out, int out_size, void* d_ws, size_t ws_size,
                              hipStream_t stream) {
    const float* x = (const float*)d_in[0];   // [65536, 512]
    const float* W = (const float*)d_in[1];   // [1024, 1536]
    const float* b = (const float*)d_in[2];   // [1536]
    float* out = (float*)d_out;

    char* ws = (char*)d_ws;
    unsigned short* xp  = (unsigned short*)(ws);                 // 67,109,888 B (+pad)
    unsigned short* Wt  = (unsigned short*)(ws + 67110912LL);    // 3,145,728 B
    unsigned short* zfo = (unsigned short*)(ws + 70256640LL);    // 201,326,592 B
    // P/L/carry reuse the xp region (dead after GEMM)
    float* P     = (float*)(ws);
    float* L     = (float*)(ws + 4194304LL);
    float* carry = (float*)(ws + 8388608LL);

    prep_x<<<4096, 256, 0, stream>>>(x, xp);
    prep_w<<<768, 256, 0, stream>>>(W, Wt);

    dim3 gg(H3 / 256, T_LEN / 128, 1);     // 6 x 512 = 3072 blocks
    gemm_gates<<<gg, 256, 0, stream>>>(xp, Wt, b, zfo);

    scan_pass1<<<NCHUNK, 128, 0, stream>>>(zfo, P, L);
    scan_pass2<<<512, 1024, 0, stream>>>(P, L, carry, out);
    scan_pass3<<<NCHUNK, 128, 0, stream>>>(zfo, carry, out);
}